// Round 2
// baseline (311.345 us; speedup 1.0000x reference)
//
#include <hip/hip_runtime.h>

// Problem constants (fixed by the reference):
//   M = 1048576 coefficient rows, K = 8 neighbors, N = 524288 GNN rows,
//   H = 524288 hier rows, B = 1, C = 16 channels.
//
// Output model (evidence R0-R5 prev session): harness compares REAL PART
// ONLY as fp32, out_size = (N+H)*C floats (67 MB). Inputs fp32/int32.
//
// R6 (verified): split preproc(interleave re|im -> 128B rows, build inv
// permutation) + natural-order main with scattered stores. 1.43 GB -> 795 MB
// total traffic, 549.6 -> 309.7 us. Budget now: ~135 us fixed harness
// overhead (R0 calibration: 549.6 dur vs 414.8 rocprof) + ~62 us preproc
// (406 MB = BW floor) + ~113 us main (FETCH 322 MB @ 3.5 TB/s fabric).
//
// R7 theory: main's gather working set (134 MB fp32 XfC) fits LLC but is 4x
// the 32 MB aggregate L2 -> ~50% of the 4.7x gather reuse is missed, and
// FETCH_SIZE counts L2->fabric. Shrink the working set: store XfH in fp16
// (inputs are N(0,1), |x|max ~5.5 -> fp16 rel err 2^-11, strictly better
// than bf16 here). 64 B/row, 67 MB footprint: halves fabric demand per
// gather and doubles effective L2 hit rate. Compute stays fp32.
// Predicted: absmax 0 -> ~2e-3; main FETCH 322->~200 MB, 113->~80 us;
// preproc WRITE 138->71 MB, ~53 us; total ~265 us.
#define GM 1048576
#define GK 8
#define GN 524288
#define GH 524288
#define GC 16

typedef float     f32x4 __attribute__((ext_vector_type(4)));
typedef _Float16  f16x4 __attribute__((ext_vector_type(4)));

#define XFH_BYTES ((size_t)GM * 32 * 2)    // 67,108,864: M rows x [16 re | 16 im] f16
#define INV_BYTES ((size_t)(GN + GH) * 4)  //  4,194,304: inverse of hier_ind

// ---------------- preproc: fp32 -> fp16 interleave + inverse permutation --
// tid < GM*8: f16x4 #tid of XfH. row=tid>>3, part=tid&7. XfH halves layout:
// row*32 + part*4 == tid*4, so stores are perfectly contiguous 8 B/lane.
// part<4 -> re channels [4p,4p+4), part>=4 -> im channels [4(p-4),...).
// Loads: 64 B contiguous per row per array (coalesced). Xf reads + hier_ind
// are read-once -> nontemporal. XfH store stays cached (re-read by main).
// tid >= GM*8: inv[hier_ind[i]] = i (coalesced read, 4 B scatter into 4 MB).
__global__ __launch_bounds__(256) void preproc_kernel(
    const f32x4* __restrict__ Xf_real,
    const f32x4* __restrict__ Xf_imag,
    const int*   __restrict__ hier_ind,
    f16x4*       __restrict__ XfH,
    int*         __restrict__ inv)
{
    const int tid = blockIdx.x * blockDim.x + threadIdx.x;
    if (tid < GM * 8) {
        const int row  = tid >> 3;
        const int part = tid & 7;
        f32x4 v;
        if (part < 4) {
            v = __builtin_nontemporal_load(Xf_real + ((size_t)row * 4 + part));
        } else {
            v = __builtin_nontemporal_load(Xf_imag + ((size_t)row * 4 + (part - 4)));
        }
        f16x4 h;
        h.x = (_Float16)v.x; h.y = (_Float16)v.y;
        h.z = (_Float16)v.z; h.w = (_Float16)v.w;
        XfH[tid] = h;
    } else {
        const int i = tid - GM * 8;        // grid sized exactly, no bound check
        const int r = __builtin_nontemporal_load(hier_ind + i);
        inv[r] = i;
    }
}

// ---------------- main: natural-order compute, scattered 64B store --------
// One quad (4 lanes) per cat-row; lane q covers channels [4q,4q+4).
// Part A (row<N): NI/w/inv reads coalesced nontemporal; 8 gathers of one
// 64 B XfH row each (quad issues 2x 8 B loads/lane, all in one line).
// Part B: hier_mask/inv coalesced; gather re-half (32 B) of XfH row.
// Output scattered 64 B rows via inv (stores don't stall).
__global__ __launch_bounds__(256) void gnn_main_kernel(
    const _Float16* __restrict__ XfH,
    const float*    __restrict__ w_real,
    const float*    __restrict__ w_imag,
    const int*      __restrict__ NI,
    const int*      __restrict__ hier_mask,
    const int*      __restrict__ inv,
    float*          __restrict__ out)
{
    const int tid = blockIdx.x * blockDim.x + threadIdx.x;
    const int row = tid >> 2;          // cat row in [0, N+H)
    const int q   = tid & 3;
    const int ch  = q * 4;             // starting channel

    f32x4 re;
    int dst;

    if (row < GN) {
        re = (f32x4)(0.f);
        #pragma unroll
        for (int k = 0; k < GK; ++k) {
            const int   idx = __builtin_nontemporal_load(NI + k * GN + row);
            const float wr  = __builtin_nontemporal_load(w_real + k * GN + row);
            const float wi  = __builtin_nontemporal_load(w_imag + k * GN + row);
            const f16x4 xr  = *(const f16x4*)(XfH + (size_t)idx * 32 + ch);
            const f16x4 xi  = *(const f16x4*)(XfH + (size_t)idx * 32 + 16 + ch);
            // real part of (xr + i*xi) * (wr + i*wi), accumulated in fp32
            re.x += (float)xr.x * wr - (float)xi.x * wi;
            re.y += (float)xr.y * wr - (float)xi.y * wi;
            re.z += (float)xr.z * wr - (float)xi.z * wi;
            re.w += (float)xr.w * wr - (float)xi.w * wi;
        }
        dst = __builtin_nontemporal_load(inv + row);
    } else {
        const int j   = row - GN;
        const int idx = __builtin_nontemporal_load(hier_mask + j);
        const f16x4 xr = *(const f16x4*)(XfH + (size_t)idx * 32 + ch);
        re.x = (float)xr.x; re.y = (float)xr.y;
        re.z = (float)xr.z; re.w = (float)xr.w;
        dst = __builtin_nontemporal_load(inv + GN + j);
    }

    __builtin_nontemporal_store(re, (f32x4*)(out + (size_t)dst * GC + ch));
}

// ---------------- fallback: R0 verified single kernel (549 us) ------------
__global__ __launch_bounds__(256) void gnn_gather_kernel(
    const float* __restrict__ Xf_real,
    const float* __restrict__ Xf_imag,
    const float* __restrict__ w_real,
    const float* __restrict__ w_imag,
    const int*   __restrict__ NI,
    const int*   __restrict__ hier_mask,
    const int*   __restrict__ hier_ind,
    float*       __restrict__ out)
{
    const int tid = blockIdx.x * blockDim.x + threadIdx.x;
    const int row = tid >> 2;
    const int q   = tid & 3;
    const int ch  = q * 4;

    const int src = hier_ind[row];

    float4 re;

    if (src < GN) {
        re = make_float4(0.f, 0.f, 0.f, 0.f);
        #pragma unroll
        for (int k = 0; k < GK; ++k) {
            const int   idx = NI[k * GN + src];
            const float wr  = w_real[k * GN + src];
            const float wi  = w_imag[k * GN + src];
            const float4 xr = *(const float4*)(Xf_real + (size_t)idx * GC + ch);
            const float4 xi = *(const float4*)(Xf_imag + (size_t)idx * GC + ch);
            re.x += xr.x * wr - xi.x * wi;
            re.y += xr.y * wr - xi.y * wi;
            re.z += xr.z * wr - xi.z * wi;
            re.w += xr.w * wr - xi.w * wi;
        }
    } else {
        const int idx = hier_mask[src - GN];
        re = *(const float4*)(Xf_real + (size_t)idx * GC + ch);
    }

    *(float4*)(out + (size_t)row * GC + ch) = re;
}

extern "C" void kernel_launch(void* const* d_in, const int* in_sizes, int n_in,
                              void* d_out, int out_size, void* d_ws, size_t ws_size,
                              hipStream_t stream) {
    const float* Xf_real   = (const float*)d_in[0];
    const float* Xf_imag   = (const float*)d_in[1];
    const float* w_real    = (const float*)d_in[2];
    const float* w_imag    = (const float*)d_in[3];
    const int*   NI        = (const int*)d_in[4];
    const int*   hier_mask = (const int*)d_in[5];
    const int*   hier_ind  = (const int*)d_in[6];
    float*       out       = (float*)d_out;

    if (d_ws != nullptr && ws_size >= XFH_BYTES + INV_BYTES) {
        _Float16* XfH = (_Float16*)d_ws;
        int*      inv = (int*)((char*)d_ws + XFH_BYTES);

        // GM*8 interleave threads + (GN+GH) inv threads = 9,437,184 = 36864*256
        const int pre_threads = GM * 8 + GN + GH;
        preproc_kernel<<<pre_threads / 256, 256, 0, stream>>>(
            (const f32x4*)Xf_real, (const f32x4*)Xf_imag, hier_ind,
            (f16x4*)XfH, inv);

        // (N+H) rows * 4 lanes/row = 4,194,304 threads -> 16384 blocks
        const int main_threads = (GN + GH) * 4;
        gnn_main_kernel<<<main_threads / 256, 256, 0, stream>>>(
            XfH, w_real, w_imag, NI, hier_mask, inv, out);
    } else {
        // workspace too small: proven fallback path
        const int total_threads = (GN + GH) * 4;
        gnn_gather_kernel<<<total_threads / 256, 256, 0, stream>>>(
            Xf_real, Xf_imag, w_real, w_imag, NI, hier_mask, hier_ind, out);
    }
}

// Round 3
// 307.110 us; speedup vs baseline: 1.0138x; 1.0138x over previous
//
#include <hip/hip_runtime.h>

// Problem constants (fixed by the reference):
//   M = 1048576 coefficient rows, K = 8 neighbors, N = 524288 GNN rows,
//   H = 524288 hier rows, B = 1, C = 16 channels.
//
// Output model (evidence R0-R5 prev session): harness compares REAL PART
// ONLY as fp32, out_size = (N+H)*C floats (67 MB). Inputs fp32/int32.
//
// R6 (verified): preproc(interleave re|im rows, build inv perm) + natural-
// order main with scattered stores: 549.6 -> 309.7 us.
// R7 (null): fp16 XfH halved footprint but FETCH only 322->313 MB, dur flat.
// Conclusion: L2-miss bytes are line-granularity-bound, not footprint-bound.
//
// R8 theory: main may be LATENCY-bound, not fabric-bound. Evidence: only
// 36 VGPRs -> ~3-4 outstanding gather misses/wave; 313 MB miss traffic is
// LLC-resident (XfH 67 MB + streams << 256 MB) so the 3.5 TB/s plateau may
// be MLP*latency, not a BW wall. Fix: phase-split gather loads (idx[4] ->
// 8 named gather regs -> FMA), two k-chunks, launch_bounds(256,8) to hold
// 8 waves/SIMD at <=64 VGPR. Target ~8 misses in flight/wave (~2.5x MLP).
// Also: preproc widened to 16 B out/thread (halves issue count).
// Predicted: FETCH unchanged ~313 MB; if MLP-bound main 110->65-80 us,
// total ~250-270; if fabric-bound, null on main (roofline evidence).
#define GM 1048576
#define GK 8
#define GN 524288
#define GH 524288
#define GC 16

typedef float     f32x4 __attribute__((ext_vector_type(4)));
typedef _Float16  f16x4 __attribute__((ext_vector_type(4)));
typedef _Float16  f16x8 __attribute__((ext_vector_type(8)));

#define XFH_BYTES ((size_t)GM * 32 * 2)    // 67,108,864: M rows x [16 re | 16 im] f16
#define INV_BYTES ((size_t)(GN + GH) * 4)  //  4,194,304: inverse of hier_ind

// ---------------- preproc: fp32 -> fp16 interleave + inverse permutation --
// tid < GM*4: 16 B chunk #tid of XfH. row=tid>>2, part=tid&3:
//   part 0 -> re[0..7], 1 -> re[8..15], 2 -> im[0..7], 3 -> im[8..15].
// Output offset row*64B + part*16B == tid*16B -> perfectly contiguous
// dwordx4 stores. Loads: 2x f32x4 contiguous per lane (coalesced).
// tid >= GM*4: inv[hier_ind[i]] = i (coalesced read, 4 B scatter into 4 MB).
__global__ __launch_bounds__(256) void preproc_kernel(
    const f32x4* __restrict__ Xf_real,
    const f32x4* __restrict__ Xf_imag,
    const int*   __restrict__ hier_ind,
    f16x8*       __restrict__ XfH8,
    int*         __restrict__ inv)
{
    const int tid = blockIdx.x * blockDim.x + threadIdx.x;
    if (tid < GM * 4) {
        const int row  = tid >> 2;
        const int part = tid & 3;
        const f32x4* src = (part < 2 ? Xf_real : Xf_imag)
                           + (size_t)row * 4 + (part & 1) * 2;
        const f32x4 a = __builtin_nontemporal_load(src);
        const f32x4 b = __builtin_nontemporal_load(src + 1);
        f16x8 h;
        h[0] = (_Float16)a.x; h[1] = (_Float16)a.y;
        h[2] = (_Float16)a.z; h[3] = (_Float16)a.w;
        h[4] = (_Float16)b.x; h[5] = (_Float16)b.y;
        h[6] = (_Float16)b.z; h[7] = (_Float16)b.w;
        XfH8[tid] = h;
    } else {
        const int i = tid - GM * 4;        // grid sized exactly, no bound check
        const int r = __builtin_nontemporal_load(hier_ind + i);
        inv[r] = i;
    }
}

// ---------------- main: natural-order, MLP-phased gathers, scatter store --
// One quad (4 lanes) per cat-row; lane q covers channels [4q,4q+4).
// Part A (row<N): per k-chunk of 4: load idx[0..3] -> issue all 8 gather
// loads into named regs -> then w loads + FMA. Keeps ~8 gather misses in
// flight per wave instead of ~3-4 (36-VGPR R7 version).
// Part B: hier_mask/inv coalesced; gather re-half (8 B/lane) of XfH row.
// Output scattered 64 B rows via inv (stores don't stall).
__global__ __launch_bounds__(256, 8) void gnn_main_kernel(
    const _Float16* __restrict__ XfH,
    const float*    __restrict__ w_real,
    const float*    __restrict__ w_imag,
    const int*      __restrict__ NI,
    const int*      __restrict__ hier_mask,
    const int*      __restrict__ inv,
    float*          __restrict__ out)
{
    const int tid = blockIdx.x * blockDim.x + threadIdx.x;
    const int row = tid >> 2;          // cat row in [0, N+H)
    const int q   = tid & 3;
    const int ch  = q * 4;             // starting channel

    f32x4 re;
    int dst;

    if (row < GN) {
        re = (f32x4)(0.f);
        const int*   nip = NI     + row;
        const float* wrp = w_real + row;
        const float* wip = w_imag + row;
        #pragma unroll
        for (int h = 0; h < 2; ++h) {
            int idx[4];
            #pragma unroll
            for (int k = 0; k < 4; ++k)
                idx[k] = __builtin_nontemporal_load(nip + (size_t)k * GN);
            f16x4 xr[4], xi[4];
            #pragma unroll
            for (int k = 0; k < 4; ++k) {
                const _Float16* p = XfH + (size_t)idx[k] * 32 + ch;
                xr[k] = *(const f16x4*)(p);
                xi[k] = *(const f16x4*)(p + 16);
            }
            #pragma unroll
            for (int k = 0; k < 4; ++k) {
                const float wr = __builtin_nontemporal_load(wrp + (size_t)k * GN);
                const float wi = __builtin_nontemporal_load(wip + (size_t)k * GN);
                re.x += (float)xr[k].x * wr - (float)xi[k].x * wi;
                re.y += (float)xr[k].y * wr - (float)xi[k].y * wi;
                re.z += (float)xr[k].z * wr - (float)xi[k].z * wi;
                re.w += (float)xr[k].w * wr - (float)xi[k].w * wi;
            }
            nip += 4 * GN; wrp += 4 * GN; wip += 4 * GN;
        }
        dst = __builtin_nontemporal_load(inv + row);
    } else {
        const int j   = row - GN;
        const int idx = __builtin_nontemporal_load(hier_mask + j);
        const f16x4 xr = *(const f16x4*)(XfH + (size_t)idx * 32 + ch);
        re.x = (float)xr.x; re.y = (float)xr.y;
        re.z = (float)xr.z; re.w = (float)xr.w;
        dst = __builtin_nontemporal_load(inv + GN + j);
    }

    __builtin_nontemporal_store(re, (f32x4*)(out + (size_t)dst * GC + ch));
}

// ---------------- fallback: R0 verified single kernel (549 us) ------------
__global__ __launch_bounds__(256) void gnn_gather_kernel(
    const float* __restrict__ Xf_real,
    const float* __restrict__ Xf_imag,
    const float* __restrict__ w_real,
    const float* __restrict__ w_imag,
    const int*   __restrict__ NI,
    const int*   __restrict__ hier_mask,
    const int*   __restrict__ hier_ind,
    float*       __restrict__ out)
{
    const int tid = blockIdx.x * blockDim.x + threadIdx.x;
    const int row = tid >> 2;
    const int q   = tid & 3;
    const int ch  = q * 4;

    const int src = hier_ind[row];

    float4 re;

    if (src < GN) {
        re = make_float4(0.f, 0.f, 0.f, 0.f);
        #pragma unroll
        for (int k = 0; k < GK; ++k) {
            const int   idx = NI[k * GN + src];
            const float wr  = w_real[k * GN + src];
            const float wi  = w_imag[k * GN + src];
            const float4 xr = *(const float4*)(Xf_real + (size_t)idx * GC + ch);
            const float4 xi = *(const float4*)(Xf_imag + (size_t)idx * GC + ch);
            re.x += xr.x * wr - xi.x * wi;
            re.y += xr.y * wr - xi.y * wi;
            re.z += xr.z * wr - xi.z * wi;
            re.w += xr.w * wr - xi.w * wi;
        }
    } else {
        const int idx = hier_mask[src - GN];
        re = *(const float4*)(Xf_real + (size_t)idx * GC + ch);
    }

    *(float4*)(out + (size_t)row * GC + ch) = re;
}

extern "C" void kernel_launch(void* const* d_in, const int* in_sizes, int n_in,
                              void* d_out, int out_size, void* d_ws, size_t ws_size,
                              hipStream_t stream) {
    const float* Xf_real   = (const float*)d_in[0];
    const float* Xf_imag   = (const float*)d_in[1];
    const float* w_real    = (const float*)d_in[2];
    const float* w_imag    = (const float*)d_in[3];
    const int*   NI        = (const int*)d_in[4];
    const int*   hier_mask = (const int*)d_in[5];
    const int*   hier_ind  = (const int*)d_in[6];
    float*       out       = (float*)d_out;

    if (d_ws != nullptr && ws_size >= XFH_BYTES + INV_BYTES) {
        _Float16* XfH = (_Float16*)d_ws;
        int*      inv = (int*)((char*)d_ws + XFH_BYTES);

        // GM*4 interleave threads + (GN+GH) inv threads = 5,242,880 = 20480*256
        const int pre_threads = GM * 4 + GN + GH;
        preproc_kernel<<<pre_threads / 256, 256, 0, stream>>>(
            (const f32x4*)Xf_real, (const f32x4*)Xf_imag, hier_ind,
            (f16x8*)XfH, inv);

        // (N+H) rows * 4 lanes/row = 4,194,304 threads -> 16384 blocks
        const int main_threads = (GN + GH) * 4;
        gnn_main_kernel<<<main_threads / 256, 256, 0, stream>>>(
            XfH, w_real, w_imag, NI, hier_mask, inv, out);
    } else {
        // workspace too small: proven fallback path
        const int total_threads = (GN + GH) * 4;
        gnn_gather_kernel<<<total_threads / 256, 256, 0, stream>>>(
            Xf_real, Xf_imag, w_real, w_imag, NI, hier_mask, hier_ind, out);
    }
}